// Round 1
// baseline (337.369 us; speedup 1.0000x reference)
//
#include <hip/hip_runtime.h>

// LinearSelfAttention: out = rot(q) @ (rot(k)^T @ (w*v)), fp16 MFMA.
// Round 4: precomputed rotary cos/sin table (f16 pairs) removes the
// sincosf + phase-einsum from the qkv epilogue (it was ~2/3 of qkv's
// VALU and qkv is VALU-bound per rocprof: MfmaUtil 18.8, VALUBusy 37.6).
//
// ws layout (~165.5 MiB):
//   phi_h  [32768][512] f16   @ 0            (33,554,432 B)  } kvp f16[8] aliases
//   wcat   [1536][512]  f16   @ 33,554,432   ( 1,572,864 B)    phi_h after qkv
//   bcat   [1536]       f32   @ 35,127,296   (     6,144 B)
//   qr     [32768][512] f16   @ 35,133,440   (33,554,432 B)
//   krT    [8][512][4096] f16 @ 68,687,872   (33,554,432 B)
//   vwT    [8][512][4096] f16 @ 102,242,304  (33,554,432 B)
//   kvT    [8][512][512] f16  @ 135,796,736  ( 4,194,304 B)
//   cs     [32768][256] f16x2 @ 139,991,040  (33,554,432 B)  end: 173,545,472

typedef _Float16 f16x8 __attribute__((ext_vector_type(8)));
typedef _Float16 f16x4 __attribute__((ext_vector_type(4)));
typedef _Float16 f16x2 __attribute__((ext_vector_type(2)));
typedef float f32x4 __attribute__((ext_vector_type(4)));

__device__ __forceinline__ void gl_lds16(const void* g, void* l) {
    __builtin_amdgcn_global_load_lds(
        (const __attribute__((address_space(1))) void*)g,
        (__attribute__((address_space(3))) void*)l, 16, 0, 0);
}

// Stage one 128x32 A-tile and B-tile (BK=32) into LDS. gA/gB point at
// (tile_row0, k0). Each wave fills 2 chunks of 16 rows per operand.
__device__ __forceinline__ void stage2(const _Float16* gA, size_t sA,
                                       const _Float16* gB, size_t sB,
                                       _Float16* As, _Float16* Bs,
                                       int ca, int srow, int sseg) {
    gl_lds16(&gA[(size_t)(ca * 16 + srow) * sA + sseg], &As[ca * 512]);
    gl_lds16(&gA[(size_t)(ca * 16 + 16 + srow) * sA + sseg], &As[(ca + 1) * 512]);
    gl_lds16(&gB[(size_t)(ca * 16 + srow) * sB + sseg], &Bs[ca * 512]);
    gl_lds16(&gB[(size_t)(ca * 16 + 16 + srow) * sB + sseg], &Bs[(ca + 1) * 512]);
}

// One BK=32 MFMA step from LDS tiles (4 waves, 64x64 per wave, 4x4 16x16).
__device__ __forceinline__ void mfma_step(const _Float16* As, const _Float16* Bs,
                                          int wm, int wn, int l16, int quad,
                                          f32x4 acc[4][4]) {
    f16x8 af[4], bf[4];
    #pragma unroll
    for (int mi = 0; mi < 4; mi++)
        af[mi] = *(const f16x8*)&As[(wm + mi * 16 + l16) * 32 + quad * 8];
    #pragma unroll
    for (int ni = 0; ni < 4; ni++)
        bf[ni] = *(const f16x8*)&Bs[(wn + ni * 16 + l16) * 32 + quad * 8];
    #pragma unroll
    for (int mi = 0; mi < 4; mi++)
        #pragma unroll
        for (int ni = 0; ni < 4; ni++)
            acc[mi][ni] = __builtin_amdgcn_mfma_f32_16x16x32_f16(
                af[mi], bf[ni], acc[mi][ni], 0, 0, 0);
}

// ---------------------------------------------------------------- prep ----
__global__ __launch_bounds__(256) void convert_phi(const float* __restrict__ phi,
                                                   _Float16* __restrict__ phi_h) {
    int i = (blockIdx.x * 256 + threadIdx.x) * 4;
    float4 v = *(const float4*)(phi + i);
    f16x4 o = {(_Float16)v.x, (_Float16)v.y, (_Float16)v.z, (_Float16)v.w};
    *(f16x4*)(phi_h + i) = o;
}

__global__ __launch_bounds__(256) void pack_w(
    const float* __restrict__ Wq, const float* __restrict__ Wk,
    const float* __restrict__ Wv, const float* __restrict__ bq,
    const float* __restrict__ bk, const float* __restrict__ bv,
    _Float16* __restrict__ wcat, float* __restrict__ bcat) {
    int j = blockIdx.x;            // 0..1535 output row
    int reg = j >> 9, jr = j & 511;
    const float* W; const float* bias;
    if (reg == 0)      { W = Wq; bias = bq; }
    else if (reg == 1) { W = Wk; bias = bk; }
    else               { W = Wv; bias = bv; }
    int d = (reg < 2) ? ((jr & 1) ? (jr >> 1) + 256 : (jr >> 1)) : jr;
    for (int i = threadIdx.x; i < 512; i += 256)
        wcat[j * 512 + i] = (_Float16)W[d * 512 + i];
    if (threadIdx.x == 0) bcat[j] = bias[d];
}

// Rotary phase table: cs[gm][jp] = (cos(ph), sin(ph)) as f16 pair, where
// ph = coords[gm] . Wrot[jp]. One block per row, one thread per pair.
__global__ __launch_bounds__(256) void rot_tab(
    const float* __restrict__ coords, const float* __restrict__ Wrot,
    f16x2* __restrict__ cs) {
    __shared__ float w[768];
    if (threadIdx.x < 192) {
        float4 v = *(const float4*)(Wrot + threadIdx.x * 4);
        *(float4*)(w + threadIdx.x * 4) = v;
    }
    __syncthreads();
    int gm = blockIdx.x;
    float x = coords[gm * 3], y = coords[gm * 3 + 1], z = coords[gm * 3 + 2];
    int j = threadIdx.x;
    float ph = x * w[j * 3] + y * w[j * 3 + 1] + z * w[j * 3 + 2];
    float sv, cv; __sincosf(ph, &sv, &cv);
    cs[(size_t)gm * 256 + j] = f16x2{(_Float16)cv, (_Float16)sv};
}

// ------------------------------------------------------------ QKV GEMM ----
// C[32768][1536] = phi_h @ wcat^T, tile 128x128, dbuf BK=32.
__global__ __launch_bounds__(256) void qkv_kernel(
    const _Float16* __restrict__ phi_h, const _Float16* __restrict__ wcat,
    const float* __restrict__ bcat, const float* __restrict__ weights,
    const f16x2* __restrict__ cs,
    _Float16* __restrict__ qr, _Float16* __restrict__ krT,
    _Float16* __restrict__ vwT) {
    __shared__ __align__(16) char smem[34816];          // Ts 128x136 f16 alias
    _Float16* As0 = (_Float16*)smem;
    _Float16* Bs0 = (_Float16*)(smem + 8192);
    _Float16* As1 = (_Float16*)(smem + 16384);
    _Float16* Bs1 = (_Float16*)(smem + 24576);
    _Float16* Ts  = (_Float16*)smem;

    const int tid = threadIdx.x;
    const int lane = tid & 63, wave = tid >> 6;
    const int quad = lane >> 4, l16 = lane & 15;
    const int wm = (wave >> 1) * 64, wn = (wave & 1) * 64;
    const int m0 = blockIdx.y * 128;      // row tile (over B*N)
    const int c0 = blockIdx.x * 128;      // col tile (over 1536)
    const int ca = wave * 2;
    const int srow = lane >> 2, sseg = (lane & 3) * 8;

    const _Float16* gA = phi_h + (size_t)m0 * 512;
    const _Float16* gB = wcat + (size_t)c0 * 512;

    f32x4 acc[4][4] = {};

    stage2(gA, 512, gB, 512, As0, Bs0, ca, srow, sseg);
    __syncthreads();
    for (int k0 = 0; k0 < 512; k0 += 64) {
        stage2(gA + k0 + 32, 512, gB + k0 + 32, 512, As1, Bs1, ca, srow, sseg);
        mfma_step(As0, Bs0, wm, wn, l16, quad, acc);
        __syncthreads();
        if (k0 + 64 < 512)
            stage2(gA + k0 + 64, 512, gB + k0 + 64, 512, As0, Bs0, ca, srow, sseg);
        mfma_step(As1, Bs1, wm, wn, l16, quad, acc);
        __syncthreads();
    }

    const int region = c0 >> 9;   // 0=q, 1=k, 2=v (128 | 512: never straddles)
    const float qscale = 0.04419417382415922f;  // 1/sqrt(512)

    float bias[4];
    int jp[4];
    #pragma unroll
    for (int ni = 0; ni < 4; ni++) {
        int gc = c0 + wn + ni * 16 + l16;
        bias[ni] = bcat[gc];
        jp[ni] = (gc & 511) >> 1;
    }

    if (region == 0) {
        // q: rotary (table) + scale -> Ts[row][col] -> coalesced qr store
        #pragma unroll
        for (int mi = 0; mi < 4; mi++)
            #pragma unroll
            for (int r = 0; r < 4; r++) {
                int row = wm + mi * 16 + quad * 4 + r;
                int gm = m0 + row;
                const f16x2* tr = cs + (size_t)gm * 256;
                #pragma unroll
                for (int ni = 0; ni < 4; ni++) {
                    float val = (acc[mi][ni][r] + bias[ni]) * qscale;
                    float part = __shfl_xor(val, 1);
                    f16x2 p = tr[jp[ni]];
                    float cv = p.x, sv = p.y;
                    float res = (l16 & 1) ? (part * sv + val * cv)
                                          : (val * cv - part * sv);
                    Ts[row * 136 + wn + ni * 16 + l16] = (_Float16)res;
                }
            }
        __syncthreads();
        for (int i = tid; i < 2048; i += 256) {
            int row = i >> 4, cv = (i & 15) * 8;
            *(f16x8*)&qr[(m0 + row) * 512 + c0 + cv] = *(f16x8*)&Ts[row * 136 + cv];
        }
    } else {
        // k: rotary (table); v: *weights. -> Ts[col][row] -> coalesced [b][col][n]
        #pragma unroll
        for (int mi = 0; mi < 4; mi++)
            #pragma unroll
            for (int r = 0; r < 4; r++) {
                int row = wm + mi * 16 + quad * 4 + r;
                int gm = m0 + row;
                if (region == 1) {
                    const f16x2* tr = cs + (size_t)gm * 256;
                    #pragma unroll
                    for (int ni = 0; ni < 4; ni++) {
                        float val = acc[mi][ni][r] + bias[ni];
                        float part = __shfl_xor(val, 1);
                        f16x2 p = tr[jp[ni]];
                        float cv = p.x, sv = p.y;
                        float res = (l16 & 1) ? (part * sv + val * cv)
                                              : (val * cv - part * sv);
                        Ts[(wn + ni * 16 + l16) * 136 + row] = (_Float16)res;
                    }
                } else {
                    float wgt = weights[gm];
                    #pragma unroll
                    for (int ni = 0; ni < 4; ni++) {
                        float val = (acc[mi][ni][r] + bias[ni]) * wgt;
                        Ts[(wn + ni * 16 + l16) * 136 + row] = (_Float16)val;
                    }
                }
            }
        __syncthreads();
        _Float16* dst = (region == 1) ? krT : vwT;
        const int b = m0 >> 12, n0 = m0 & 4095, cb = c0 & 511;
        for (int i = tid; i < 2048; i += 256) {
            int col = i >> 4, rv = (i & 15) * 8;
            *(f16x8*)&dst[((size_t)b * 512 + cb + col) * 4096 + n0 + rv] =
                *(f16x8*)&Ts[col * 136 + rv];
        }
    }
}

// ------------------------------------------------------------- kv GEMM ----
// kvp[s][b][e][d] (f16) = sum_{n in split s} vwT[b][e][n]*krT[b][d][n];
// tile 128x128, split-K x8 (K=512 each), dbuf BK=32.
__global__ __launch_bounds__(256) void kv_kernel(
    const _Float16* __restrict__ vwT, const _Float16* __restrict__ krT,
    _Float16* __restrict__ kvp) {
    __shared__ __align__(16) char smem[32768];
    _Float16* As0 = (_Float16*)smem;
    _Float16* Bs0 = (_Float16*)(smem + 8192);
    _Float16* As1 = (_Float16*)(smem + 16384);
    _Float16* Bs1 = (_Float16*)(smem + 24576);
    const int tid = threadIdx.x, lane = tid & 63, wave = tid >> 6;
    const int quad = lane >> 4, l16 = lane & 15;
    const int wm = (wave >> 1) * 64, wn = (wave & 1) * 64;
    const int d0 = blockIdx.x * 128, e0 = blockIdx.y * 128;
    const int b = blockIdx.z >> 3, split = blockIdx.z & 7;
    const int ca = wave * 2;
    const int srow = lane >> 2, sseg = (lane & 3) * 8;
    const size_t base = (size_t)b * 512 * 4096;
    const int kbeg = split * 512;
    const _Float16* gA = vwT + base + (size_t)e0 * 4096 + kbeg;
    const _Float16* gB = krT + base + (size_t)d0 * 4096 + kbeg;
    f32x4 acc[4][4] = {};

    stage2(gA, 4096, gB, 4096, As0, Bs0, ca, srow, sseg);
    __syncthreads();
    for (int k0 = 0; k0 < 512; k0 += 64) {
        stage2(gA + k0 + 32, 4096, gB + k0 + 32, 4096, As1, Bs1, ca, srow, sseg);
        mfma_step(As0, Bs0, wm, wn, l16, quad, acc);
        __syncthreads();
        if (k0 + 64 < 512)
            stage2(gA + k0 + 64, 4096, gB + k0 + 64, 4096, As0, Bs0, ca, srow, sseg);
        mfma_step(As1, Bs1, wm, wn, l16, quad, acc);
        __syncthreads();
    }

    _Float16* dst = kvp + ((size_t)split * 8 + b) * 262144;
    #pragma unroll
    for (int mi = 0; mi < 4; mi++)
        #pragma unroll
        for (int ni = 0; ni < 4; ni++)
            #pragma unroll
            for (int r = 0; r < 4; r++) {
                int e = e0 + wm + mi * 16 + quad * 4 + r;
                int d = d0 + wn + ni * 16 + l16;
                dst[e * 512 + d] = (_Float16)acc[mi][ni][r];
            }
}

// kvT[b][e][d] f16 = sum_s kvp[s][b][e][d]
__global__ __launch_bounds__(256) void reduce_kv(const _Float16* __restrict__ kvp,
                                                 _Float16* __restrict__ kvT) {
    int i = (blockIdx.x * 256 + threadIdx.x) * 8;
    float s[8] = {};
    #pragma unroll
    for (int sp = 0; sp < 8; sp++) {
        f16x8 v = *(const f16x8*)(kvp + (size_t)sp * 2097152 + i);
        #pragma unroll
        for (int j = 0; j < 8; j++) s[j] += (float)v[j];
    }
    f16x8 o;
    #pragma unroll
    for (int j = 0; j < 8; j++) o[j] = (_Float16)s[j];
    *(f16x8*)(kvT + i) = o;
}

// ------------------------------------------------------------ out GEMM ----
// out[gm][e] = sum_d qr[gm][d] * kvT[b][e][d]; tile 128x128, dbuf BK=32.
__global__ __launch_bounds__(256) void out_kernel(
    const _Float16* __restrict__ qr, const _Float16* __restrict__ kvT,
    float* __restrict__ out) {
    __shared__ __align__(16) char smem[32768];
    _Float16* As0 = (_Float16*)smem;
    _Float16* Bs0 = (_Float16*)(smem + 8192);
    _Float16* As1 = (_Float16*)(smem + 16384);
    _Float16* Bs1 = (_Float16*)(smem + 24576);
    const int tid = threadIdx.x, lane = tid & 63, wave = tid >> 6;
    const int quad = lane >> 4, l16 = lane & 15;
    const int wm = (wave >> 1) * 64, wn = (wave & 1) * 64;
    const int m0 = blockIdx.y * 128, e0 = blockIdx.x * 128;
    const int b = m0 >> 12;
    const int ca = wave * 2;
    const int srow = lane >> 2, sseg = (lane & 3) * 8;
    const _Float16* gA = qr + (size_t)m0 * 512;
    const _Float16* gB = kvT + (size_t)b * 262144 + (size_t)e0 * 512;
    f32x4 acc[4][4] = {};

    stage2(gA, 512, gB, 512, As0, Bs0, ca, srow, sseg);
    __syncthreads();
    for (int k0 = 0; k0 < 512; k0 += 64) {
        stage2(gA + k0 + 32, 512, gB + k0 + 32, 512, As1, Bs1, ca, srow, sseg);
        mfma_step(As0, Bs0, wm, wn, l16, quad, acc);
        __syncthreads();
        if (k0 + 64 < 512)
            stage2(gA + k0 + 64, 512, gB + k0 + 64, 512, As0, Bs0, ca, srow, sseg);
        mfma_step(As1, Bs1, wm, wn, l16, quad, acc);
        __syncthreads();
    }

    #pragma unroll
    for (int mi = 0; mi < 4; mi++)
        #pragma unroll
        for (int ni = 0; ni < 4; ni++)
            #pragma unroll
            for (int r = 0; r < 4; r++) {
                int gm = m0 + wm + mi * 16 + quad * 4 + r;
                int e = e0 + wn + ni * 16 + l16;
                out[(size_t)gm * 512 + e] = acc[mi][ni][r];
            }
}

// -------------------------------------------------------------- launch ----
extern "C" void kernel_launch(void* const* d_in, const int* in_sizes, int n_in,
                              void* d_out, int out_size, void* d_ws, size_t ws_size,
                              hipStream_t stream) {
    const float* phi     = (const float*)d_in[0];
    const float* coords  = (const float*)d_in[1];
    const float* weights = (const float*)d_in[2];
    const float* Wq      = (const float*)d_in[3];
    const float* bq      = (const float*)d_in[4];
    const float* Wk      = (const float*)d_in[5];
    const float* bk      = (const float*)d_in[6];
    const float* Wv      = (const float*)d_in[7];
    const float* bv      = (const float*)d_in[8];
    const float* Wrot    = (const float*)d_in[9];
    float* out = (float*)d_out;

    char* ws = (char*)d_ws;
    _Float16* phi_h = (_Float16*)(ws);
    _Float16* kvp   = (_Float16*)(ws);            // aliases phi_h (dead by then)
    _Float16* wcat  = (_Float16*)(ws + 33554432);
    float*    bcat  = (float*)   (ws + 35127296);
    _Float16* qr    = (_Float16*)(ws + 35133440);
    _Float16* krT   = (_Float16*)(ws + 68687872);
    _Float16* vwT   = (_Float16*)(ws + 102242304);
    _Float16* kvT   = (_Float16*)(ws + 135796736);
    f16x2*    cst   = (f16x2*)   (ws + 139991040);  // end: 173,545,472 B

    convert_phi<<<16384, 256, 0, stream>>>(phi, phi_h);
    pack_w<<<1536, 256, 0, stream>>>(Wq, Wk, Wv, bq, bk, bv, wcat, bcat);
    rot_tab<<<32768, 256, 0, stream>>>(coords, Wrot, cst);
    qkv_kernel<<<dim3(12, 256), 256, 0, stream>>>(phi_h, wcat, bcat, weights,
                                                  cst, qr, krT, vwT);
    kv_kernel<<<dim3(4, 4, 64), 256, 0, stream>>>(vwT, krT, kvp);
    reduce_kv<<<1024, 256, 0, stream>>>(kvp, kvT);
    out_kernel<<<dim3(4, 256), 256, 0, stream>>>(qr, kvT, out);
}

// Round 2
// 332.361 us; speedup vs baseline: 1.0151x; 1.0151x over previous
//
#include <hip/hip_runtime.h>

// LinearSelfAttention: out = rot(q) @ (rot(k)^T @ (w*v)), fp16 MFMA.
// Round 5: XOR-swizzled LDS tiles (T2). The mfma_step fragment reads
// As[row*64B + quad*16B] were an 8-way bank conflict (all 16 lanes of a
// quarter-wave at addr mod 128 in {0,64}): SQ_LDS_BANK_CONFLICT 7.73M,
// LDS pipe ~85% of batch time. Swizzle: slot ^= (row>>1)&3, applied on
// the global SOURCE address (global_load_lds writes linearly) and on the
// read slot (per-thread constant -> zero dynamic cost).
//
// ws layout (~165.5 MiB):
//   phi_h  [32768][512] f16   @ 0            (33,554,432 B)  } kvp f16[8] aliases
//   wcat   [1536][512]  f16   @ 33,554,432   ( 1,572,864 B)    phi_h after qkv
//   bcat   [1536]       f32   @ 35,127,296   (     6,144 B)
//   qr     [32768][512] f16   @ 35,133,440   (33,554,432 B)
//   krT    [8][512][4096] f16 @ 68,687,872   (33,554,432 B)
//   vwT    [8][512][4096] f16 @ 102,242,304  (33,554,432 B)
//   kvT    [8][512][512] f16  @ 135,796,736  ( 4,194,304 B)
//   cs     [32768][256] f16x2 @ 139,991,040  (33,554,432 B)  end: 173,545,472

typedef _Float16 f16x8 __attribute__((ext_vector_type(8)));
typedef _Float16 f16x4 __attribute__((ext_vector_type(4)));
typedef _Float16 f16x2 __attribute__((ext_vector_type(2)));
typedef float f32x4 __attribute__((ext_vector_type(4)));

__device__ __forceinline__ void gl_lds16(const void* g, void* l) {
    __builtin_amdgcn_global_load_lds(
        (const __attribute__((address_space(1))) void*)g,
        (__attribute__((address_space(3))) void*)l, 16, 0, 0);
}

// Stage one 128x32 A-tile and B-tile (BK=32) into LDS. gA/gB point at
// (tile_row0, k0). Each wave fills 2 chunks of 16 rows per operand.
// sseg carries the inverse swizzle (slot ^ (row>>1)&3 within each 64B row)
// so the linear LDS write lands swizzled data.
__device__ __forceinline__ void stage2(const _Float16* gA, size_t sA,
                                       const _Float16* gB, size_t sB,
                                       _Float16* As, _Float16* Bs,
                                       int ca, int srow, int sseg) {
    gl_lds16(&gA[(size_t)(ca * 16 + srow) * sA + sseg], &As[ca * 512]);
    gl_lds16(&gA[(size_t)(ca * 16 + 16 + srow) * sA + sseg], &As[(ca + 1) * 512]);
    gl_lds16(&gB[(size_t)(ca * 16 + srow) * sB + sseg], &Bs[ca * 512]);
    gl_lds16(&gB[(size_t)(ca * 16 + 16 + srow) * sB + sseg], &Bs[(ca + 1) * 512]);
}

// One BK=32 MFMA step from LDS tiles (4 waves, 64x64 per wave, 4x4 16x16).
// qs = quad ^ ((l16>>1)&3): swizzled slot, per-thread constant. Row bases
// (wm/wn + mi*16) are multiples of 16, so (row>>1)&3 == (l16>>1)&3.
__device__ __forceinline__ void mfma_step(const _Float16* As, const _Float16* Bs,
                                          int wm, int wn, int l16, int qs,
                                          f32x4 acc[4][4]) {
    f16x8 af[4], bf[4];
    #pragma unroll
    for (int mi = 0; mi < 4; mi++)
        af[mi] = *(const f16x8*)&As[(wm + mi * 16 + l16) * 32 + qs * 8];
    #pragma unroll
    for (int ni = 0; ni < 4; ni++)
        bf[ni] = *(const f16x8*)&Bs[(wn + ni * 16 + l16) * 32 + qs * 8];
    #pragma unroll
    for (int mi = 0; mi < 4; mi++)
        #pragma unroll
        for (int ni = 0; ni < 4; ni++)
            acc[mi][ni] = __builtin_amdgcn_mfma_f32_16x16x32_f16(
                af[mi], bf[ni], acc[mi][ni], 0, 0, 0);
}

// ---------------------------------------------------------------- prep ----
__global__ __launch_bounds__(256) void convert_phi(const float* __restrict__ phi,
                                                   _Float16* __restrict__ phi_h) {
    int i = (blockIdx.x * 256 + threadIdx.x) * 4;
    float4 v = *(const float4*)(phi + i);
    f16x4 o = {(_Float16)v.x, (_Float16)v.y, (_Float16)v.z, (_Float16)v.w};
    *(f16x4*)(phi_h + i) = o;
}

__global__ __launch_bounds__(256) void pack_w(
    const float* __restrict__ Wq, const float* __restrict__ Wk,
    const float* __restrict__ Wv, const float* __restrict__ bq,
    const float* __restrict__ bk, const float* __restrict__ bv,
    _Float16* __restrict__ wcat, float* __restrict__ bcat) {
    int j = blockIdx.x;            // 0..1535 output row
    int reg = j >> 9, jr = j & 511;
    const float* W; const float* bias;
    if (reg == 0)      { W = Wq; bias = bq; }
    else if (reg == 1) { W = Wk; bias = bk; }
    else               { W = Wv; bias = bv; }
    int d = (reg < 2) ? ((jr & 1) ? (jr >> 1) + 256 : (jr >> 1)) : jr;
    for (int i = threadIdx.x; i < 512; i += 256)
        wcat[j * 512 + i] = (_Float16)W[d * 512 + i];
    if (threadIdx.x == 0) bcat[j] = bias[d];
}

// Rotary phase table: cs[gm][jp] = (cos(ph), sin(ph)) as f16 pair, where
// ph = coords[gm] . Wrot[jp]. One block per row, one thread per pair.
__global__ __launch_bounds__(256) void rot_tab(
    const float* __restrict__ coords, const float* __restrict__ Wrot,
    f16x2* __restrict__ cs) {
    __shared__ float w[768];
    if (threadIdx.x < 192) {
        float4 v = *(const float4*)(Wrot + threadIdx.x * 4);
        *(float4*)(w + threadIdx.x * 4) = v;
    }
    __syncthreads();
    int gm = blockIdx.x;
    float x = coords[gm * 3], y = coords[gm * 3 + 1], z = coords[gm * 3 + 2];
    int j = threadIdx.x;
    float ph = x * w[j * 3] + y * w[j * 3 + 1] + z * w[j * 3 + 2];
    float sv, cv; __sincosf(ph, &sv, &cv);
    cs[(size_t)gm * 256 + j] = f16x2{(_Float16)cv, (_Float16)sv};
}

// ------------------------------------------------------------ QKV GEMM ----
// C[32768][1536] = phi_h @ wcat^T, tile 128x128, dbuf BK=32.
__global__ __launch_bounds__(256) void qkv_kernel(
    const _Float16* __restrict__ phi_h, const _Float16* __restrict__ wcat,
    const float* __restrict__ bcat, const float* __restrict__ weights,
    const f16x2* __restrict__ cs,
    _Float16* __restrict__ qr, _Float16* __restrict__ krT,
    _Float16* __restrict__ vwT) {
    __shared__ __align__(16) char smem[34816];          // Ts 128x136 f16 alias
    _Float16* As0 = (_Float16*)smem;
    _Float16* Bs0 = (_Float16*)(smem + 8192);
    _Float16* As1 = (_Float16*)(smem + 16384);
    _Float16* Bs1 = (_Float16*)(smem + 24576);
    _Float16* Ts  = (_Float16*)smem;

    const int tid = threadIdx.x;
    const int lane = tid & 63, wave = tid >> 6;
    const int quad = lane >> 4, l16 = lane & 15;
    const int qs = quad ^ ((l16 >> 1) & 3);           // swizzled read slot
    const int wm = (wave >> 1) * 64, wn = (wave & 1) * 64;
    const int m0 = blockIdx.y * 128;      // row tile (over B*N)
    const int c0 = blockIdx.x * 128;      // col tile (over 1536)
    const int ca = wave * 2;
    const int srow = lane >> 2;
    const int sseg = (((lane & 3) ^ ((lane >> 3) & 3)) * 8);  // inv-swizzled src

    const _Float16* gA = phi_h + (size_t)m0 * 512;
    const _Float16* gB = wcat + (size_t)c0 * 512;

    f32x4 acc[4][4] = {};

    stage2(gA, 512, gB, 512, As0, Bs0, ca, srow, sseg);
    __syncthreads();
    for (int k0 = 0; k0 < 512; k0 += 64) {
        stage2(gA + k0 + 32, 512, gB + k0 + 32, 512, As1, Bs1, ca, srow, sseg);
        mfma_step(As0, Bs0, wm, wn, l16, qs, acc);
        __syncthreads();
        if (k0 + 64 < 512)
            stage2(gA + k0 + 64, 512, gB + k0 + 64, 512, As0, Bs0, ca, srow, sseg);
        mfma_step(As1, Bs1, wm, wn, l16, qs, acc);
        __syncthreads();
    }

    const int region = c0 >> 9;   // 0=q, 1=k, 2=v (128 | 512: never straddles)
    const float qscale = 0.04419417382415922f;  // 1/sqrt(512)

    float bias[4];
    int jp[4];
    #pragma unroll
    for (int ni = 0; ni < 4; ni++) {
        int gc = c0 + wn + ni * 16 + l16;
        bias[ni] = bcat[gc];
        jp[ni] = (gc & 511) >> 1;
    }

    if (region == 0) {
        // q: rotary (table) + scale -> Ts[row][col] -> coalesced qr store
        #pragma unroll
        for (int mi = 0; mi < 4; mi++)
            #pragma unroll
            for (int r = 0; r < 4; r++) {
                int row = wm + mi * 16 + quad * 4 + r;
                int gm = m0 + row;
                const f16x2* tr = cs + (size_t)gm * 256;
                #pragma unroll
                for (int ni = 0; ni < 4; ni++) {
                    float val = (acc[mi][ni][r] + bias[ni]) * qscale;
                    float part = __shfl_xor(val, 1);
                    f16x2 p = tr[jp[ni]];
                    float cv = p.x, sv = p.y;
                    float res = (l16 & 1) ? (part * sv + val * cv)
                                          : (val * cv - part * sv);
                    Ts[row * 136 + wn + ni * 16 + l16] = (_Float16)res;
                }
            }
        __syncthreads();
        for (int i = tid; i < 2048; i += 256) {
            int row = i >> 4, cv = (i & 15) * 8;
            *(f16x8*)&qr[(m0 + row) * 512 + c0 + cv] = *(f16x8*)&Ts[row * 136 + cv];
        }
    } else {
        // k: rotary (table); v: *weights. -> Ts[col][row] -> coalesced [b][col][n]
        #pragma unroll
        for (int mi = 0; mi < 4; mi++)
            #pragma unroll
            for (int r = 0; r < 4; r++) {
                int row = wm + mi * 16 + quad * 4 + r;
                int gm = m0 + row;
                if (region == 1) {
                    const f16x2* tr = cs + (size_t)gm * 256;
                    #pragma unroll
                    for (int ni = 0; ni < 4; ni++) {
                        float val = acc[mi][ni][r] + bias[ni];
                        float part = __shfl_xor(val, 1);
                        f16x2 p = tr[jp[ni]];
                        float cv = p.x, sv = p.y;
                        float res = (l16 & 1) ? (part * sv + val * cv)
                                              : (val * cv - part * sv);
                        Ts[(wn + ni * 16 + l16) * 136 + row] = (_Float16)res;
                    }
                } else {
                    float wgt = weights[gm];
                    #pragma unroll
                    for (int ni = 0; ni < 4; ni++) {
                        float val = (acc[mi][ni][r] + bias[ni]) * wgt;
                        Ts[(wn + ni * 16 + l16) * 136 + row] = (_Float16)val;
                    }
                }
            }
        __syncthreads();
        _Float16* dst = (region == 1) ? krT : vwT;
        const int b = m0 >> 12, n0 = m0 & 4095, cb = c0 & 511;
        for (int i = tid; i < 2048; i += 256) {
            int col = i >> 4, rv = (i & 15) * 8;
            *(f16x8*)&dst[((size_t)b * 512 + cb + col) * 4096 + n0 + rv] =
                *(f16x8*)&Ts[col * 136 + rv];
        }
    }
}

// ------------------------------------------------------------- kv GEMM ----
// kvp[s][b][e][d] (f16) = sum_{n in split s} vwT[b][e][n]*krT[b][d][n];
// tile 128x128, split-K x8 (K=512 each), dbuf BK=32.
__global__ __launch_bounds__(256) void kv_kernel(
    const _Float16* __restrict__ vwT, const _Float16* __restrict__ krT,
    _Float16* __restrict__ kvp) {
    __shared__ __align__(16) char smem[32768];
    _Float16* As0 = (_Float16*)smem;
    _Float16* Bs0 = (_Float16*)(smem + 8192);
    _Float16* As1 = (_Float16*)(smem + 16384);
    _Float16* Bs1 = (_Float16*)(smem + 24576);
    const int tid = threadIdx.x, lane = tid & 63, wave = tid >> 6;
    const int quad = lane >> 4, l16 = lane & 15;
    const int qs = quad ^ ((l16 >> 1) & 3);
    const int wm = (wave >> 1) * 64, wn = (wave & 1) * 64;
    const int d0 = blockIdx.x * 128, e0 = blockIdx.y * 128;
    const int b = blockIdx.z >> 3, split = blockIdx.z & 7;
    const int ca = wave * 2;
    const int srow = lane >> 2;
    const int sseg = (((lane & 3) ^ ((lane >> 3) & 3)) * 8);
    const size_t base = (size_t)b * 512 * 4096;
    const int kbeg = split * 512;
    const _Float16* gA = vwT + base + (size_t)e0 * 4096 + kbeg;
    const _Float16* gB = krT + base + (size_t)d0 * 4096 + kbeg;
    f32x4 acc[4][4] = {};

    stage2(gA, 4096, gB, 4096, As0, Bs0, ca, srow, sseg);
    __syncthreads();
    for (int k0 = 0; k0 < 512; k0 += 64) {
        stage2(gA + k0 + 32, 4096, gB + k0 + 32, 4096, As1, Bs1, ca, srow, sseg);
        mfma_step(As0, Bs0, wm, wn, l16, qs, acc);
        __syncthreads();
        if (k0 + 64 < 512)
            stage2(gA + k0 + 64, 4096, gB + k0 + 64, 4096, As0, Bs0, ca, srow, sseg);
        mfma_step(As1, Bs1, wm, wn, l16, qs, acc);
        __syncthreads();
    }

    _Float16* dst = kvp + ((size_t)split * 8 + b) * 262144;
    #pragma unroll
    for (int mi = 0; mi < 4; mi++)
        #pragma unroll
        for (int ni = 0; ni < 4; ni++)
            #pragma unroll
            for (int r = 0; r < 4; r++) {
                int e = e0 + wm + mi * 16 + quad * 4 + r;
                int d = d0 + wn + ni * 16 + l16;
                dst[e * 512 + d] = (_Float16)acc[mi][ni][r];
            }
}

// kvT[b][e][d] f16 = sum_s kvp[s][b][e][d]
__global__ __launch_bounds__(256) void reduce_kv(const _Float16* __restrict__ kvp,
                                                 _Float16* __restrict__ kvT) {
    int i = (blockIdx.x * 256 + threadIdx.x) * 8;
    float s[8] = {};
    #pragma unroll
    for (int sp = 0; sp < 8; sp++) {
        f16x8 v = *(const f16x8*)(kvp + (size_t)sp * 2097152 + i);
        #pragma unroll
        for (int j = 0; j < 8; j++) s[j] += (float)v[j];
    }
    f16x8 o;
    #pragma unroll
    for (int j = 0; j < 8; j++) o[j] = (_Float16)s[j];
    *(f16x8*)(kvT + i) = o;
}

// ------------------------------------------------------------ out GEMM ----
// out[gm][e] = sum_d qr[gm][d] * kvT[b][e][d]; tile 128x128, dbuf BK=32.
__global__ __launch_bounds__(256) void out_kernel(
    const _Float16* __restrict__ qr, const _Float16* __restrict__ kvT,
    float* __restrict__ out) {
    __shared__ __align__(16) char smem[32768];
    _Float16* As0 = (_Float16*)smem;
    _Float16* Bs0 = (_Float16*)(smem + 8192);
    _Float16* As1 = (_Float16*)(smem + 16384);
    _Float16* Bs1 = (_Float16*)(smem + 24576);
    const int tid = threadIdx.x, lane = tid & 63, wave = tid >> 6;
    const int quad = lane >> 4, l16 = lane & 15;
    const int qs = quad ^ ((l16 >> 1) & 3);
    const int wm = (wave >> 1) * 64, wn = (wave & 1) * 64;
    const int m0 = blockIdx.y * 128, e0 = blockIdx.x * 128;
    const int b = m0 >> 12;
    const int ca = wave * 2;
    const int srow = lane >> 2;
    const int sseg = (((lane & 3) ^ ((lane >> 3) & 3)) * 8);
    const _Float16* gA = qr + (size_t)m0 * 512;
    const _Float16* gB = kvT + (size_t)b * 262144 + (size_t)e0 * 512;
    f32x4 acc[4][4] = {};

    stage2(gA, 512, gB, 512, As0, Bs0, ca, srow, sseg);
    __syncthreads();
    for (int k0 = 0; k0 < 512; k0 += 64) {
        stage2(gA + k0 + 32, 512, gB + k0 + 32, 512, As1, Bs1, ca, srow, sseg);
        mfma_step(As0, Bs0, wm, wn, l16, qs, acc);
        __syncthreads();
        if (k0 + 64 < 512)
            stage2(gA + k0 + 64, 512, gB + k0 + 64, 512, As0, Bs0, ca, srow, sseg);
        mfma_step(As1, Bs1, wm, wn, l16, qs, acc);
        __syncthreads();
    }

    #pragma unroll
    for (int mi = 0; mi < 4; mi++)
        #pragma unroll
        for (int ni = 0; ni < 4; ni++)
            #pragma unroll
            for (int r = 0; r < 4; r++) {
                int gm = m0 + wm + mi * 16 + quad * 4 + r;
                int e = e0 + wn + ni * 16 + l16;
                out[(size_t)gm * 512 + e] = acc[mi][ni][r];
            }
}

// -------------------------------------------------------------- launch ----
extern "C" void kernel_launch(void* const* d_in, const int* in_sizes, int n_in,
                              void* d_out, int out_size, void* d_ws, size_t ws_size,
                              hipStream_t stream) {
    const float* phi     = (const float*)d_in[0];
    const float* coords  = (const float*)d_in[1];
    const float* weights = (const float*)d_in[2];
    const float* Wq      = (const float*)d_in[3];
    const float* bq      = (const float*)d_in[4];
    const float* Wk      = (const float*)d_in[5];
    const float* bk      = (const float*)d_in[6];
    const float* Wv      = (const float*)d_in[7];
    const float* bv      = (const float*)d_in[8];
    const float* Wrot    = (const float*)d_in[9];
    float* out = (float*)d_out;

    char* ws = (char*)d_ws;
    _Float16* phi_h = (_Float16*)(ws);
    _Float16* kvp   = (_Float16*)(ws);            // aliases phi_h (dead by then)
    _Float16* wcat  = (_Float16*)(ws + 33554432);
    float*    bcat  = (float*)   (ws + 35127296);
    _Float16* qr    = (_Float16*)(ws + 35133440);
    _Float16* krT   = (_Float16*)(ws + 68687872);
    _Float16* vwT   = (_Float16*)(ws + 102242304);
    _Float16* kvT   = (_Float16*)(ws + 135796736);
    f16x2*    cst   = (f16x2*)   (ws + 139991040);  // end: 173,545,472 B

    convert_phi<<<16384, 256, 0, stream>>>(phi, phi_h);
    pack_w<<<1536, 256, 0, stream>>>(Wq, Wk, Wv, bq, bk, bv, wcat, bcat);
    rot_tab<<<32768, 256, 0, stream>>>(coords, Wrot, cst);
    qkv_kernel<<<dim3(12, 256), 256, 0, stream>>>(phi_h, wcat, bcat, weights,
                                                  cst, qr, krT, vwT);
    kv_kernel<<<dim3(4, 4, 64), 256, 0, stream>>>(vwT, krT, kvp);
    reduce_kv<<<1024, 256, 0, stream>>>(kvp, kvT);
    out_kernel<<<dim3(4, 256), 256, 0, stream>>>(qr, kvT, out);
}

// Round 4
// 310.939 us; speedup vs baseline: 1.0850x; 1.0689x over previous
//
#include <hip/hip_runtime.h>

// LinearSelfAttention: out = rot(q) @ (rot(k)^T @ (w*v)), fp16 MFMA.
// Round 7: R6's counted-vmcnt pipeline RACED (absmax 37.9): raw s_barrier
// is IntrNoMem, so LDS reads hoisted above the pre-MFMA barrier and the
// MFMA+lgkmcnt group sank below the reads-done barrier (rule #18).
// Fix: pin every barrier -- vmcnt asm -> s_barrier -> ""-clobber +
// sched_barrier(0) before MFMA; lgkmcnt(0) + sched_barrier(0) ->
// s_barrier -> ""-clobber before restage. vmcnt ledger unchanged
// (depth-2, vmcnt(4) per phase, vmcnt(0) final).
// LDS XOR swizzle kept (R2: conflicts 7.73M -> 1.44M).
//
// ws layout (~133.5 MiB):
//   phi_h  [32768][512] f16   @ 0            (33,554,432 B)  } kvp f16[8] aliases
//   wcat   [1536][512]  f16   @ 33,554,432   ( 1,572,864 B)    phi_h after qkv
//   bcat   [1536]       f32   @ 35,127,296   (     6,144 B)
//   qr     [32768][512] f16   @ 35,133,440   (33,554,432 B)
//   krT    [8][512][4096] f16 @ 68,687,872   (33,554,432 B)
//   vwT    [8][512][4096] f16 @ 102,242,304  (33,554,432 B)
//   kvT    [8][512][512] f16  @ 135,796,736  ( 4,194,304 B)

typedef _Float16 f16x8 __attribute__((ext_vector_type(8)));
typedef _Float16 f16x4 __attribute__((ext_vector_type(4)));
typedef float f32x4 __attribute__((ext_vector_type(4)));

__device__ __forceinline__ void gl_lds16(const void* g, void* l) {
    __builtin_amdgcn_global_load_lds(
        (const __attribute__((address_space(1))) void*)g,
        (__attribute__((address_space(3))) void*)l, 16, 0, 0);
}

// Stage one 128x32 A-tile and B-tile (BK=32) into LDS (4 global_load_lds
// per wave = 4 vmcnt events). sseg carries the inverse XOR swizzle
// (slot ^ (row>>1)&3 within each 64B row) so the linear LDS write lands
// swizzled data.
__device__ __forceinline__ void stage2(const _Float16* gA, size_t sA,
                                       const _Float16* gB, size_t sB,
                                       _Float16* As, _Float16* Bs,
                                       int ca, int srow, int sseg) {
    gl_lds16(&gA[(size_t)(ca * 16 + srow) * sA + sseg], &As[ca * 512]);
    gl_lds16(&gA[(size_t)(ca * 16 + 16 + srow) * sA + sseg], &As[(ca + 1) * 512]);
    gl_lds16(&gB[(size_t)(ca * 16 + srow) * sB + sseg], &Bs[ca * 512]);
    gl_lds16(&gB[(size_t)(ca * 16 + 16 + srow) * sB + sseg], &Bs[(ca + 1) * 512]);
}

// One BK=32 MFMA step from LDS tiles (4 waves, 64x64 per wave, 4x4 16x16).
// qs = quad ^ ((l16>>1)&3): swizzled slot, per-thread constant.
__device__ __forceinline__ void mfma_step(const _Float16* As, const _Float16* Bs,
                                          int wm, int wn, int l16, int qs,
                                          f32x4 acc[4][4]) {
    f16x8 af[4], bf[4];
    #pragma unroll
    for (int mi = 0; mi < 4; mi++)
        af[mi] = *(const f16x8*)&As[(wm + mi * 16 + l16) * 32 + qs * 8];
    #pragma unroll
    for (int ni = 0; ni < 4; ni++)
        bf[ni] = *(const f16x8*)&Bs[(wn + ni * 16 + l16) * 32 + qs * 8];
    #pragma unroll
    for (int mi = 0; mi < 4; mi++)
        #pragma unroll
        for (int ni = 0; ni < 4; ni++)
            acc[mi][ni] = __builtin_amdgcn_mfma_f32_16x16x32_f16(
                af[mi], bf[ni], acc[mi][ni], 0, 0, 0);
}

// One pipeline phase. Invariants:
//  - vmcnt(VM) + barrier: with every wave having <=VM outstanding after
//    retiring its own 4 loads of the tile to consume, barrier-join =>
//    the whole tile (all waves' chunks) has landed in LDS.
//  - lgkmcnt(0) + sched_barrier + barrier: every wave's LDS reads of the
//    buffer are COMPLETE (data in VGPRs) before any wave may restage it.
// The ""-clobber after each s_barrier stops LDS reads hoisting above it
// (s_barrier is IntrNoMem); sched_barrier(0) stops the machine scheduler
// moving the MFMA/lgkmcnt group across the phase boundary (rule #18).
#define PHASE(BUFA, BUFB, VM)                                                 \
    asm volatile("s_waitcnt vmcnt(" #VM ")" ::: "memory");                    \
    __builtin_amdgcn_s_barrier();                                             \
    asm volatile("" ::: "memory");                                            \
    __builtin_amdgcn_sched_barrier(0);                                        \
    mfma_step(BUFA, BUFB, wm, wn, l16, qs, acc);                              \
    asm volatile("s_waitcnt lgkmcnt(0)" ::: "memory");                        \
    __builtin_amdgcn_sched_barrier(0);                                        \
    __builtin_amdgcn_s_barrier();                                             \
    asm volatile("" ::: "memory");

// Pipelined K=512 loop: 16 BK=32 tiles, ping-pong As0/As1, depth-2
// prefetch, counted vmcnt (4 = one tile's loads still in flight).
#define PIPE_LOOP(gA, sA, gB, sB)                                             \
    stage2(gA, sA, gB, sB, As0, Bs0, ca, srow, sseg);                         \
    stage2(gA + 32, sA, gB + 32, sB, As1, Bs1, ca, srow, sseg);               \
    _Pragma("unroll")                                                         \
    for (int p = 0; p < 8; p++) {                                             \
        const int t0 = 2 * p;                                                 \
        PHASE(As0, Bs0, 4)                                                    \
        if (t0 + 2 < 16)                                                      \
            stage2(gA + (size_t)(t0 + 2) * 32, sA,                            \
                   gB + (size_t)(t0 + 2) * 32, sB,                            \
                   As0, Bs0, ca, srow, sseg);                                 \
        if (p < 7) { PHASE(As1, Bs1, 4) }                                     \
        else       { PHASE(As1, Bs1, 0) }                                     \
        if (t0 + 3 < 16)                                                      \
            stage2(gA + (size_t)(t0 + 3) * 32, sA,                            \
                   gB + (size_t)(t0 + 3) * 32, sB,                            \
                   As1, Bs1, ca, srow, sseg);                                 \
    }

// ---------------------------------------------------------------- prep ----
__global__ __launch_bounds__(256) void convert_phi(const float* __restrict__ phi,
                                                   _Float16* __restrict__ phi_h) {
    int i = (blockIdx.x * 256 + threadIdx.x) * 4;
    float4 v = *(const float4*)(phi + i);
    f16x4 o = {(_Float16)v.x, (_Float16)v.y, (_Float16)v.z, (_Float16)v.w};
    *(f16x4*)(phi_h + i) = o;
}

__global__ __launch_bounds__(256) void pack_w(
    const float* __restrict__ Wq, const float* __restrict__ Wk,
    const float* __restrict__ Wv, const float* __restrict__ bq,
    const float* __restrict__ bk, const float* __restrict__ bv,
    _Float16* __restrict__ wcat, float* __restrict__ bcat) {
    int j = blockIdx.x;            // 0..1535 output row
    int reg = j >> 9, jr = j & 511;
    const float* W; const float* bias;
    if (reg == 0)      { W = Wq; bias = bq; }
    else if (reg == 1) { W = Wk; bias = bk; }
    else               { W = Wv; bias = bv; }
    int d = (reg < 2) ? ((jr & 1) ? (jr >> 1) + 256 : (jr >> 1)) : jr;
    for (int i = threadIdx.x; i < 512; i += 256)
        wcat[j * 512 + i] = (_Float16)W[d * 512 + i];
    if (threadIdx.x == 0) bcat[j] = bias[d];
}

// ------------------------------------------------------------ QKV GEMM ----
// C[32768][1536] = phi_h @ wcat^T, tile 128x128, pipelined BK=32.
__global__ __launch_bounds__(256) void qkv_kernel(
    const _Float16* __restrict__ phi_h, const _Float16* __restrict__ wcat,
    const float* __restrict__ bcat, const float* __restrict__ coords,
    const float* __restrict__ weights, const float* __restrict__ Wrot,
    _Float16* __restrict__ qr, _Float16* __restrict__ krT,
    _Float16* __restrict__ vwT) {
    __shared__ __align__(16) char smem[34816];          // Ts 128x136 f16 alias
    _Float16* As0 = (_Float16*)smem;
    _Float16* Bs0 = (_Float16*)(smem + 8192);
    _Float16* As1 = (_Float16*)(smem + 16384);
    _Float16* Bs1 = (_Float16*)(smem + 24576);
    _Float16* Ts  = (_Float16*)smem;

    const int tid = threadIdx.x;
    const int lane = tid & 63, wave = tid >> 6;
    const int quad = lane >> 4, l16 = lane & 15;
    const int qs = quad ^ ((l16 >> 1) & 3);           // swizzled read slot
    const int wm = (wave >> 1) * 64, wn = (wave & 1) * 64;
    const int m0 = blockIdx.y * 128;      // row tile (over B*N)
    const int c0 = blockIdx.x * 128;      // col tile (over 1536)
    const int ca = wave * 2;
    const int srow = lane >> 2;
    const int sseg = (((lane & 3) ^ ((lane >> 3) & 3)) * 8);  // inv-swizzled src

    const _Float16* gA = phi_h + (size_t)m0 * 512;
    const _Float16* gB = wcat + (size_t)c0 * 512;

    f32x4 acc[4][4] = {};

    PIPE_LOOP(gA, 512, gB, 512)

    const int region = c0 >> 9;   // 0=q, 1=k, 2=v (128 | 512: never straddles)
    const float qscale = 0.04419417382415922f;  // 1/sqrt(512)

    float bias[4], w0[4], w1[4], w2[4];
    #pragma unroll
    for (int ni = 0; ni < 4; ni++) {
        int gc = c0 + wn + ni * 16 + l16;
        bias[ni] = bcat[gc];
        if (region < 2) {
            int jp = (gc & 511) >> 1;
            w0[ni] = Wrot[jp * 3];
            w1[ni] = Wrot[jp * 3 + 1];
            w2[ni] = Wrot[jp * 3 + 2];
        }
    }

    if (region == 0) {
        // q: rotary + scale -> Ts[row][col] -> coalesced qr store
        #pragma unroll
        for (int mi = 0; mi < 4; mi++)
            #pragma unroll
            for (int r = 0; r < 4; r++) {
                int row = wm + mi * 16 + quad * 4 + r;
                int gm = m0 + row;
                float x = coords[gm * 3], y = coords[gm * 3 + 1], z = coords[gm * 3 + 2];
                #pragma unroll
                for (int ni = 0; ni < 4; ni++) {
                    float val = (acc[mi][ni][r] + bias[ni]) * qscale;
                    float part = __shfl_xor(val, 1);
                    float ph = x * w0[ni] + y * w1[ni] + z * w2[ni];
                    float sv, cv; __sincosf(ph, &sv, &cv);
                    float res = (l16 & 1) ? (part * sv + val * cv)
                                          : (val * cv - part * sv);
                    Ts[row * 136 + wn + ni * 16 + l16] = (_Float16)res;
                }
            }
        __syncthreads();
        for (int i = tid; i < 2048; i += 256) {
            int row = i >> 4, cv = (i & 15) * 8;
            *(f16x8*)&qr[(m0 + row) * 512 + c0 + cv] = *(f16x8*)&Ts[row * 136 + cv];
        }
    } else {
        // k: rotary; v: *weights. -> Ts[col][row] -> coalesced [b][col][n]
        #pragma unroll
        for (int mi = 0; mi < 4; mi++)
            #pragma unroll
            for (int r = 0; r < 4; r++) {
                int row = wm + mi * 16 + quad * 4 + r;
                int gm = m0 + row;
                if (region == 1) {
                    float x = coords[gm * 3], y = coords[gm * 3 + 1], z = coords[gm * 3 + 2];
                    #pragma unroll
                    for (int ni = 0; ni < 4; ni++) {
                        float val = acc[mi][ni][r] + bias[ni];
                        float part = __shfl_xor(val, 1);
                        float ph = x * w0[ni] + y * w1[ni] + z * w2[ni];
                        float sv, cv; __sincosf(ph, &sv, &cv);
                        float res = (l16 & 1) ? (part * sv + val * cv)
                                              : (val * cv - part * sv);
                        Ts[(wn + ni * 16 + l16) * 136 + row] = (_Float16)res;
                    }
                } else {
                    float wgt = weights[gm];
                    #pragma unroll
                    for (int ni = 0; ni < 4; ni++) {
                        float val = (acc[mi][ni][r] + bias[ni]) * wgt;
                        Ts[(wn + ni * 16 + l16) * 136 + row] = (_Float16)val;
                    }
                }
            }
        __syncthreads();
        _Float16* dst = (region == 1) ? krT : vwT;
        const int b = m0 >> 12, n0 = m0 & 4095, cb = c0 & 511;
        for (int i = tid; i < 2048; i += 256) {
            int col = i >> 4, rv = (i & 15) * 8;
            *(f16x8*)&dst[((size_t)b * 512 + cb + col) * 4096 + n0 + rv] =
                *(f16x8*)&Ts[col * 136 + rv];
        }
    }
}

// ------------------------------------------------------------- kv GEMM ----
// kvp[s][b][e][d] (f16) = sum_{n in split s} vwT[b][e][n]*krT[b][d][n];
// tile 128x128, split-K x8 (K=512 each), pipelined BK=32.
__global__ __launch_bounds__(256) void kv_kernel(
    const _Float16* __restrict__ vwT, const _Float16* __restrict__ krT,
    _Float16* __restrict__ kvp) {
    __shared__ __align__(16) char smem[32768];
    _Float16* As0 = (_Float16*)smem;
    _Float16* Bs0 = (_Float16*)(smem + 8192);
    _Float16* As1 = (_Float16*)(smem + 16384);
    _Float16* Bs1 = (_Float16*)(smem + 24576);
    const int tid = threadIdx.x, lane = tid & 63, wave = tid >> 6;
    const int quad = lane >> 4, l16 = lane & 15;
    const int qs = quad ^ ((l16 >> 1) & 3);
    const int wm = (wave >> 1) * 64, wn = (wave & 1) * 64;
    const int d0 = blockIdx.x * 128, e0 = blockIdx.y * 128;
    const int b = blockIdx.z >> 3, split = blockIdx.z & 7;
    const int ca = wave * 2;
    const int srow = lane >> 2;
    const int sseg = (((lane & 3) ^ ((lane >> 3) & 3)) * 8);
    const size_t base = (size_t)b * 512 * 4096;
    const int kbeg = split * 512;
    const _Float16* gA = vwT + base + (size_t)e0 * 4096 + kbeg;
    const _Float16* gB = krT + base + (size_t)d0 * 4096 + kbeg;
    f32x4 acc[4][4] = {};

    PIPE_LOOP(gA, 4096, gB, 4096)

    _Float16* dst = kvp + ((size_t)split * 8 + b) * 262144;
    #pragma unroll
    for (int mi = 0; mi < 4; mi++)
        #pragma unroll
        for (int ni = 0; ni < 4; ni++)
            #pragma unroll
            for (int r = 0; r < 4; r++) {
                int e = e0 + wm + mi * 16 + quad * 4 + r;
                int d = d0 + wn + ni * 16 + l16;
                dst[e * 512 + d] = (_Float16)acc[mi][ni][r];
            }
}

// kvT[b][e][d] f16 = sum_s kvp[s][b][e][d]
__global__ __launch_bounds__(256) void reduce_kv(const _Float16* __restrict__ kvp,
                                                 _Float16* __restrict__ kvT) {
    int i = (blockIdx.x * 256 + threadIdx.x) * 8;
    float s[8] = {};
    #pragma unroll
    for (int sp = 0; sp < 8; sp++) {
        f16x8 v = *(const f16x8*)(kvp + (size_t)sp * 2097152 + i);
        #pragma unroll
        for (int j = 0; j < 8; j++) s[j] += (float)v[j];
    }
    f16x8 o;
    #pragma unroll
    for (int j = 0; j < 8; j++) o[j] = (_Float16)s[j];
    *(f16x8*)(kvT + i) = o;
}

// ------------------------------------------------------------ out GEMM ----
// out[gm][e] = sum_d qr[gm][d] * kvT[b][e][d]; tile 128x128, pipelined BK=32.
__global__ __launch_bounds__(256) void out_kernel(
    const _Float16* __restrict__ qr, const _Float16* __restrict__ kvT,
    float* __restrict__ out) {
    __shared__ __align__(16) char smem[32768];
    _Float16* As0 = (_Float16*)smem;
    _Float16* Bs0 = (_Float16*)(smem + 8192);
    _Float16* As1 = (_Float16*)(smem + 16384);
    _Float16* Bs1 = (_Float16*)(smem + 24576);
    const int tid = threadIdx.x, lane = tid & 63, wave = tid >> 6;
    const int quad = lane >> 4, l16 = lane & 15;
    const int qs = quad ^ ((l16 >> 1) & 3);
    const int wm = (wave >> 1) * 64, wn = (wave & 1) * 64;
    const int m0 = blockIdx.y * 128, e0 = blockIdx.x * 128;
    const int b = m0 >> 12;
    const int ca = wave * 2;
    const int srow = lane >> 2;
    const int sseg = (((lane & 3) ^ ((lane >> 3) & 3)) * 8);
    const _Float16* gA = qr + (size_t)m0 * 512;
    const _Float16* gB = kvT + (size_t)b * 262144 + (size_t)e0 * 512;
    f32x4 acc[4][4] = {};

    PIPE_LOOP(gA, 512, gB, 512)

    #pragma unroll
    for (int mi = 0; mi < 4; mi++)
        #pragma unroll
        for (int ni = 0; ni < 4; ni++)
            #pragma unroll
            for (int r = 0; r < 4; r++) {
                int gm = m0 + wm + mi * 16 + quad * 4 + r;
                int e = e0 + wn + ni * 16 + l16;
                out[(size_t)gm * 512 + e] = acc[mi][ni][r];
            }
}

// -------------------------------------------------------------- launch ----
extern "C" void kernel_launch(void* const* d_in, const int* in_sizes, int n_in,
                              void* d_out, int out_size, void* d_ws, size_t ws_size,
                              hipStream_t stream) {
    const float* phi     = (const float*)d_in[0];
    const float* coords  = (const float*)d_in[1];
    const float* weights = (const float*)d_in[2];
    const float* Wq      = (const float*)d_in[3];
    const float* bq      = (const float*)d_in[4];
    const float* Wk      = (const float*)d_in[5];
    const float* bk      = (const float*)d_in[6];
    const float* Wv      = (const float*)d_in[7];
    const float* bv      = (const float*)d_in[8];
    const float* Wrot    = (const float*)d_in[9];
    float* out = (float*)d_out;

    char* ws = (char*)d_ws;
    _Float16* phi_h = (_Float16*)(ws);
    _Float16* kvp   = (_Float16*)(ws);            // aliases phi_h (dead by then)
    _Float16* wcat  = (_Float16*)(ws + 33554432);
    float*    bcat  = (float*)   (ws + 35127296);
    _Float16* qr    = (_Float16*)(ws + 35133440);
    _Float16* krT   = (_Float16*)(ws + 68687872);
    _Float16* vwT   = (_Float16*)(ws + 102242304);
    _Float16* kvT   = (_Float16*)(ws + 135796736);  // end: 139,991,040 B

    convert_phi<<<16384, 256, 0, stream>>>(phi, phi_h);
    pack_w<<<1536, 256, 0, stream>>>(Wq, Wk, Wv, bq, bk, bv, wcat, bcat);
    qkv_kernel<<<dim3(12, 256), 256, 0, stream>>>(phi_h, wcat, bcat, coords,
                                                  weights, Wrot, qr, krT, vwT);
    kv_kernel<<<dim3(4, 4, 64), 256, 0, stream>>>(vwT, krT, kvp);
    reduce_kv<<<1024, 256, 0, stream>>>(kvp, kvT);
    out_kernel<<<dim3(4, 256), 256, 0, stream>>>(qr, kvT, out);
}